// Round 3
// baseline (73.889 us; speedup 1.0000x reference)
//
#include <hip/hip_runtime.h>

// ImprovedBilateralFilter3D — 96^3 fp32, fully fused single kernel.
//
// Per block: 32x4x4 output tile.
//   Stage A: load 36x8x8 volume tile (halo 2) into LDS, zero outside bounds
//            (Sobel uses zero padding).
//   Stage B: 3-channel Sobel (cross-correlation) over 34x6x6 grad region
//            (output tile + halo 1) into LDS.
//   Stage C: 27-neighbor bilateral, edge-clamped coords (always inside the
//            loaded halo), fused spatial+range weight in one __expf.
// LDS: 9216 + 14688 = 23.9 KB -> 6 blocks/CU.

#define NV 96
#define NV2 (NV * NV)

#define TX 32
#define TY 4
#define TZ 4
#define VX (TX + 4)  // 36
#define VY (TY + 4)  // 8
#define VZ (TZ + 4)  // 8
#define GX (TX + 2)  // 34
#define GY (TY + 2)  // 6
#define GZ (TZ + 2)  // 6

__global__ __launch_bounds__(256) void fused_bilateral_kernel(
    const float* __restrict__ vol, float* __restrict__ out) {
    __shared__ float sv[VZ][VY][VX];         // raw volume, zero-padded
    __shared__ float sg[GZ][GY][GX][3];      // Sobel gradient (stride-3: conflict-free)

    const int X0 = blockIdx.x * TX;
    const int Y0 = blockIdx.y * TY;
    const int Z0 = blockIdx.z * TZ;
    const int t = threadIdx.x;

    // ---- Stage A: volume tile + halo 2, zero outside global bounds ----
    for (int li = t; li < VX * VY * VZ; li += 256) {
        int lx = li % VX;
        int lyz = li / VX;
        int ly = lyz % VY;
        int lz = lyz / VY;
        int gx = X0 - 2 + lx;
        int gy = Y0 - 2 + ly;
        int gz = Z0 - 2 + lz;
        float v = 0.0f;
        if (gx >= 0 && gx < NV && gy >= 0 && gy < NV && gz >= 0 && gz < NV)
            v = vol[gz * NV2 + gy * NV + gx];
        sv[lz][ly][lx] = v;
    }
    __syncthreads();

    // ---- Stage B: Sobel over grad region (output tile + halo 1) ----
    // grad global origin = (X0-1, Y0-1, Z0-1); vol local of grad local g is g+1.
    for (int li = t; li < GX * GY * GZ; li += 256) {
        int lx = li % GX;
        int lyz = li / GX;
        int ly = lyz % GY;
        int lz = lyz / GY;
        float gh = 0.0f, gw = 0.0f, gd = 0.0f;
#pragma unroll
        for (int a = 0; a < 3; ++a) {  // z offset index (dz = a-1)
            const float sma = (a == 1) ? 0.5f : 0.25f;
            const float dva = (a == 0) ? 1.0f : ((a == 2) ? -1.0f : 0.0f);
#pragma unroll
            for (int b = 0; b < 3; ++b) {  // y offset index
                const float smb = (b == 1) ? 0.5f : 0.25f;
                const float dvb = (b == 0) ? 1.0f : ((b == 2) ? -1.0f : 0.0f);
                float v0 = sv[lz + a][ly + b][lx + 0];
                float v1 = sv[lz + a][ly + b][lx + 1];
                float v2 = sv[lz + a][ly + b][lx + 2];
                float xs = 0.25f * v0 + 0.5f * v1 + 0.25f * v2;  // smooth in x
                float xd = v0 - v2;                              // deriv in x
                gh += dva * smb * xs;
                gw += sma * dvb * xs;
                gd += sma * smb * xd;
            }
        }
        sg[lz][ly][lx][0] = gh;
        sg[lz][ly][lx][1] = gw;
        sg[lz][ly][lx][2] = gd;
    }
    __syncthreads();

    // ---- Stage C: bilateral, 2 output voxels per thread (z and z+2) ----
    const int tx = t & 31;
    const int ty = (t >> 5) & 3;
    const int tzh = t >> 7;  // 0..1

    const float inv2sd = 1.0f / (2.0f * 120.0f * 120.0f);
    const float inv2sr = 1.0f / (2.0f * 1.2f * 1.2f);

    const int ox = X0 + tx;
    const int oy = Y0 + ty;
    const int oz0 = Z0 + tzh;
    const int oz1 = oz0 + 2;

    // center gradients (grad lds coord = global - (origin-1) => tile-local+1)
    const float c0x = sg[tzh + 1][ty + 1][tx + 1][0];
    const float c0y = sg[tzh + 1][ty + 1][tx + 1][1];
    const float c0z = sg[tzh + 1][ty + 1][tx + 1][2];
    const float c1x = sg[tzh + 3][ty + 1][tx + 1][0];
    const float c1y = sg[tzh + 3][ty + 1][tx + 1][1];
    const float c1z = sg[tzh + 3][ty + 1][tx + 1][2];

    float num0 = 0.0f, den0 = 0.0f, num1 = 0.0f, den1 = 0.0f;

#pragma unroll
    for (int dz = -1; dz <= 1; ++dz) {
        // vol-LDS z coords (edge-clamped global, then rebased to X0-2 origin)
        int nz0 = min(max(oz0 + dz, 0), NV - 1) - (Z0 - 2);
        int nz1 = min(max(oz1 + dz, 0), NV - 1) - (Z0 - 2);
#pragma unroll
        for (int dy = -1; dy <= 1; ++dy) {
            int nyv = min(max(oy + dy, 0), NV - 1) - (Y0 - 2);
            float sdzy = (float)(dz * dz + dy * dy);
#pragma unroll
            for (int dx = -1; dx <= 1; ++dx) {
                int nxv = min(max(ox + dx, 0), NV - 1) - (X0 - 2);
                float sd = sdzy + (float)(dx * dx);

                // voxel 0
                {
                    float val = sv[nz0][nyv][nxv];
                    float qx = sg[nz0 - 1][nyv - 1][nxv - 1][0];
                    float qy = sg[nz0 - 1][nyv - 1][nxv - 1][1];
                    float qz = sg[nz0 - 1][nyv - 1][nxv - 1][2];
                    float a = c0x - qx, b = c0y - qy, e = c0z - qz;
                    float g = a * a + b * b + e * e;
                    float w = __expf(-(sd * inv2sd + g * inv2sr));
                    num0 += w * val;
                    den0 += w;
                }
                // voxel 1
                {
                    float val = sv[nz1][nyv][nxv];
                    float qx = sg[nz1 - 1][nyv - 1][nxv - 1][0];
                    float qy = sg[nz1 - 1][nyv - 1][nxv - 1][1];
                    float qz = sg[nz1 - 1][nyv - 1][nxv - 1][2];
                    float a = c1x - qx, b = c1y - qy, e = c1z - qz;
                    float g = a * a + b * b + e * e;
                    float w = __expf(-(sd * inv2sd + g * inv2sr));
                    num1 += w * val;
                    den1 += w;
                }
            }
        }
    }

    out[oz0 * NV2 + oy * NV + ox] = num0 / fmaxf(den0, 1e-8f);
    out[oz1 * NV2 + oy * NV + ox] = num1 / fmaxf(den1, 1e-8f);
}

extern "C" void kernel_launch(void* const* d_in, const int* in_sizes, int n_in,
                              void* d_out, int out_size, void* d_ws, size_t ws_size,
                              hipStream_t stream) {
    const float* vol = (const float*)d_in[0];
    float* out = (float*)d_out;

    dim3 grid(NV / TX, NV / TY, NV / TZ);  // 3 x 24 x 24 = 1728 blocks
    fused_bilateral_kernel<<<grid, dim3(256), 0, stream>>>(vol, out);
}

// Round 4
// 73.829 us; speedup vs baseline: 1.0008x; 1.0008x over previous
//
#include <hip/hip_runtime.h>

// ImprovedBilateralFilter3D — 96^3 fp32, fully fused single kernel.
//
// Per block: 32x4x4 output tile.
//   Stage A: load 36x8x8 volume tile (halo 2) into LDS, zero outside bounds
//            (Sobel uses zero padding).
//   Stage B: 3-channel Sobel (cross-correlation) over 34x6x6 region
//            (output tile + halo 1); packed with the center value as
//            float4{gh, gw, gd, val} -> one ds_read_b128 per neighbor.
//   Stage C: 27-neighbor bilateral, edge-clamped coords. 2 voxels/thread
//            (z, z+2) sharing the overlapping z+1 plane: 45 b128 reads
//            instead of 54. Fused spatial+range weight in one __expf
//            (spatial term is a compile-time constant per offset).
// LDS: 9216 (sv) + 19584 (sq) = 28.8 KB -> 5 blocks/CU.

#define NV 96
#define NV2 (NV * NV)

#define TX 32
#define TY 4
#define TZ 4
#define VX (TX + 4)  // 36
#define VY (TY + 4)  // 8
#define VZ (TZ + 4)  // 8
#define GX (TX + 2)  // 34
#define GY (TY + 2)  // 6
#define GZ (TZ + 2)  // 6

__global__ __launch_bounds__(256) void fused_bilateral_kernel(
    const float* __restrict__ vol, float* __restrict__ out) {
    __shared__ float sv[VZ][VY][VX];     // raw volume, zero-padded
    __shared__ float4 sq[GZ][GY][GX];    // {gh, gw, gd, val}

    const int X0 = blockIdx.x * TX;
    const int Y0 = blockIdx.y * TY;
    const int Z0 = blockIdx.z * TZ;
    const int t = threadIdx.x;

    // ---- Stage A: volume tile + halo 2, zero outside global bounds ----
    for (int li = t; li < VX * VY * VZ; li += 256) {
        int lx = li % VX;
        int lyz = li / VX;
        int ly = lyz % VY;
        int lz = lyz / VY;
        int gx = X0 - 2 + lx;
        int gy = Y0 - 2 + ly;
        int gz = Z0 - 2 + lz;
        float v = 0.0f;
        if (gx >= 0 && gx < NV && gy >= 0 && gy < NV && gz >= 0 && gz < NV)
            v = vol[gz * NV2 + gy * NV + gx];
        sv[lz][ly][lx] = v;
    }
    __syncthreads();

    // ---- Stage B: Sobel over output tile + halo 1, packed float4 ----
    // grad global origin = (X0-1, Y0-1, Z0-1); vol-local of grad-local g is g+1.
    for (int li = t; li < GX * GY * GZ; li += 256) {
        int lx = li % GX;
        int lyz = li / GX;
        int ly = lyz % GY;
        int lz = lyz / GY;
        float gh = 0.0f, gw = 0.0f, gd = 0.0f;
#pragma unroll
        for (int a = 0; a < 3; ++a) {  // z offset index (dz = a-1)
            const float sma = (a == 1) ? 0.5f : 0.25f;
            const float dva = (a == 0) ? 1.0f : ((a == 2) ? -1.0f : 0.0f);
#pragma unroll
            for (int b = 0; b < 3; ++b) {  // y offset index
                const float smb = (b == 1) ? 0.5f : 0.25f;
                const float dvb = (b == 0) ? 1.0f : ((b == 2) ? -1.0f : 0.0f);
                float v0 = sv[lz + a][ly + b][lx + 0];
                float v1 = sv[lz + a][ly + b][lx + 1];
                float v2 = sv[lz + a][ly + b][lx + 2];
                float xs = 0.25f * v0 + 0.5f * v1 + 0.25f * v2;  // smooth in x
                float xd = v0 - v2;                              // deriv in x
                gh += dva * smb * xs;
                gw += sma * dvb * xs;
                gd += sma * smb * xd;
            }
        }
        float cv = sv[lz + 1][ly + 1][lx + 1];  // center value at this coord
        sq[lz][ly][lx] = make_float4(gh, gw, gd, cv);
    }
    __syncthreads();

    // ---- Stage C: bilateral, 2 output voxels per thread (z and z+2) ----
    const int tx = t & 31;
    const int ty = (t >> 5) & 3;
    const int tzh = t >> 7;  // 0..1

    const float inv2sd = 1.0f / (2.0f * 120.0f * 120.0f);
    const float inv2sr = 1.0f / (2.0f * 1.2f * 1.2f);

    const int ox = X0 + tx;
    const int oy = Y0 + ty;
    const int oz0 = Z0 + tzh;
    const int oz1 = oz0 + 2;

    // center packed grads: grad-local = abs - (Z0-1) = tile-local + 1
    const float4 c0 = sq[tzh + 1][ty + 1][tx + 1];
    const float4 c1 = sq[tzh + 3][ty + 1][tx + 1];

    // precompute clamped grad-local coords (all indices compile-time after
    // unroll -> stays in registers)
    int nx[3], ny[3], nz[5];
#pragma unroll
    for (int d = 0; d < 3; ++d) {
        nx[d] = min(max(ox + d - 1, 0), NV - 1) - (X0 - 1);
        ny[d] = min(max(oy + d - 1, 0), NV - 1) - (Y0 - 1);
    }
#pragma unroll
    for (int p = 0; p < 5; ++p)
        nz[p] = min(max(oz0 + p - 1, 0), NV - 1) - (Z0 - 1);

    float num0 = 0.0f, den0 = 0.0f, num1 = 0.0f, den1 = 0.0f;

#pragma unroll
    for (int p = 0; p < 5; ++p) {  // absolute plane oz0-1+p
#pragma unroll
        for (int iy = 0; iy < 3; ++iy) {
#pragma unroll
            for (int ix = 0; ix < 3; ++ix) {
                float4 q = sq[nz[p]][ny[iy]][nx[ix]];
                if (p <= 2) {  // voxel0: dz = p-1
                    const float sdc =
                        (float)((p - 1) * (p - 1) + (iy - 1) * (iy - 1) +
                                (ix - 1) * (ix - 1)) * inv2sd;
                    float a = c0.x - q.x, b = c0.y - q.y, e = c0.z - q.z;
                    float g = a * a + b * b + e * e;
                    float w = __expf(-(sdc + g * inv2sr));
                    num0 += w * q.w;
                    den0 += w;
                }
                if (p >= 2) {  // voxel1: dz = p-3
                    const float sdc =
                        (float)((p - 3) * (p - 3) + (iy - 1) * (iy - 1) +
                                (ix - 1) * (ix - 1)) * inv2sd;
                    float a = c1.x - q.x, b = c1.y - q.y, e = c1.z - q.z;
                    float g = a * a + b * b + e * e;
                    float w = __expf(-(sdc + g * inv2sr));
                    num1 += w * q.w;
                    den1 += w;
                }
            }
        }
    }

    out[oz0 * NV2 + oy * NV + ox] = num0 / fmaxf(den0, 1e-8f);
    out[oz1 * NV2 + oy * NV + ox] = num1 / fmaxf(den1, 1e-8f);
}

extern "C" void kernel_launch(void* const* d_in, const int* in_sizes, int n_in,
                              void* d_out, int out_size, void* d_ws, size_t ws_size,
                              hipStream_t stream) {
    const float* vol = (const float*)d_in[0];
    float* out = (float*)d_out;

    dim3 grid(NV / TX, NV / TY, NV / TZ);  // 3 x 24 x 24 = 1728 blocks
    fused_bilateral_kernel<<<grid, dim3(256), 0, stream>>>(vol, out);
}